// Round 3
// baseline (85.843 us; speedup 1.0000x reference)
//
#include <hip/hip_runtime.h>

#define IN_FEATURES 4096
#define OUT_FEATURES 11008
#define KO 128            // k-tiles per partition (2048/16)
#define NW 32             // int32 words per trellis block
#define SEG 16            // split-k segments per partition
#define KO_PER_SEG (KO / SEG)  // 8

// One thread owns one output row (tx) of a 16x16 tile, for 4 batch rows.
// Wave = 4 m-tiles x 16 rows, walking the same k columns in lockstep so x
// addresses are wave-uniform. Decode: idx[s] = 9-bit window ending at
// chunk s of the kv=4 bitstream; thread's row tx needs trellis words
// 2tx-1, 2tx, 2tx+1. Word 2tx-1 comes from lane tx-1 via shfl_up.
//
// Round-3 structure: minimize live registers (fit <85 VGPR under
// __launch_bounds__(256,6) with NO spill):
//  - x loaded as per-j float2 (8 floats live) instead of xs[4][16] (64)
//  - LUT split SoA: lut0/lut1, two ds_read_b32 over all 32 banks
//    (vs ds_read_b64 over 16 bank pairs: ~8-way -> ~4-way conflicts)
//  - trellis int2s for the whole segment still loaded upfront (one
//    latency window), neighbor word via shfl_up (no extra VMEM)
__global__ __launch_bounds__(256, 6) void tcq_kernel(
    const float* __restrict__ inp,       // [4][4096]
    const int* __restrict__ trellis1,    // [688*128][32]
    const int* __restrict__ trellis2,    // [688*128][32]
    const float* __restrict__ tlut,      // [512][2]
    float* __restrict__ out)             // [4][11008], pre-zeroed
{
    __shared__ float lut0[512];
    __shared__ float lut1[512];
    {
        const float2* src = reinterpret_cast<const float2*>(tlut);
        float2 a = src[threadIdx.x];
        float2 b = src[threadIdx.x + 256];
        lut0[threadIdx.x]       = a.x;
        lut1[threadIdx.x]       = a.y;
        lut0[threadIdx.x + 256] = b.x;
        lut1[threadIdx.x + 256] = b.y;
    }
    __syncthreads();

    const int tid  = threadIdx.x;
    const int lane = tid & 63;
    const int wid  = tid >> 6;
    const int tx   = lane & 15;          // row within tile
    const int mt   = lane >> 4;          // m-tile within wave (0..3)
    const int mo   = blockIdx.x * 16 + wid * 4 + mt;   // global m-tile (0..687)
    const int m    = mo * 16 + tx;       // output row
    const int ko0  = blockIdx.y * KO_PER_SEG;
    const int part = blockIdx.z;

    const int* __restrict__ tre =
        (part ? trellis2 : trellis1) + (mo * KO + ko0) * NW + 2 * tx;
    const float* __restrict__ xbase = inp + part * 2048 + ko0 * 16;

    // ---- all trellis words for this segment: one HBM latency window
    int2 w[KO_PER_SEG];
    #pragma unroll
    for (int kk = 0; kk < KO_PER_SEG; ++kk)
        w[kk] = *reinterpret_cast<const int2*>(tre + kk * NW);

    // ---- neighbor word (2tx-1) = lane tx-1's w.y; 0 for tx==0
    int wm1[KO_PER_SEG];
    #pragma unroll
    for (int kk = 0; kk < KO_PER_SEG; ++kk) {
        int t = __shfl_up(w[kk].y, 1, 16);
        wm1[kk] = (tx == 0) ? 0 : t;
    }

    // even-k and odd-k partial sums per batch (8 independent FMA chains)
    float accE[4] = {0.f, 0.f, 0.f, 0.f};
    float accO[4] = {0.f, 0.f, 0.f, 0.f};

    #pragma unroll
    for (int kk = 0; kk < KO_PER_SEG; ++kk) {
        unsigned comb0 = (unsigned(wm1[kk])  << 16) | (unsigned(w[kk].x) & 0xFFFFu);
        unsigned comb1 = (unsigned(w[kk].x) << 16) | (unsigned(w[kk].y) & 0xFFFFu);

        // batch the 16 b32 LUT gathers so lgkmcnt waits stage
        float wv0[8], wv1[8];
        #pragma unroll
        for (int j = 0; j < 8; ++j) {
            unsigned comb = (j < 4) ? comb0 : comb1;
            const int shift = 12 - 4 * (j & 3);
            unsigned idx = (comb >> shift) & 0x1FFu;
            wv0[j] = lut0[idx];
            wv1[j] = lut1[idx];
        }

        // x per j: 4 batch rows x float2 -> only 8 x-floats live at a time
        const float* xt = xbase + kk * 16;
        #pragma unroll
        for (int j = 0; j < 8; ++j) {
            #pragma unroll
            for (int b = 0; b < 4; ++b) {
                float2 xv = *reinterpret_cast<const float2*>(
                    xt + b * IN_FEATURES + 2 * j);
                accE[b] = fmaf(wv0[j], xv.x, accE[b]);
                accO[b] = fmaf(wv1[j], xv.y, accO[b]);
            }
        }
    }

    #pragma unroll
    for (int b = 0; b < 4; ++b) {
        atomicAdd(&out[b * OUT_FEATURES + m], accE[b] + accO[b]);
    }
}

extern "C" void kernel_launch(void* const* d_in, const int* in_sizes, int n_in,
                              void* d_out, int out_size, void* d_ws, size_t ws_size,
                              hipStream_t stream) {
    const float* inp  = (const float*)d_in[0];
    const int*   t1   = (const int*)d_in[1];
    const int*   t2   = (const int*)d_in[2];
    const float* tlut = (const float*)d_in[3];
    float* out = (float*)d_out;

    hipMemsetAsync(out, 0, (size_t)out_size * sizeof(float), stream);

    dim3 grid(43, SEG, 2);   // 43 groups of 16 m-tiles, 16 k-segments, 2 partitions
    dim3 block(256);
    hipLaunchKernelGGL(tcq_kernel, grid, block, 0, stream,
                       inp, t1, t2, tlut, out);
}

// Round 4
// 85.696 us; speedup vs baseline: 1.0017x; 1.0017x over previous
//
#include <hip/hip_runtime.h>

#define IN_FEATURES 4096
#define OUT_FEATURES 11008
#define KO 128            // k-tiles per partition (2048/16)
#define NW 32             // int32 words per trellis block
#define SEG 32            // split-k segments per partition
#define KO_PER_SEG (KO / SEG)  // 4

// One thread owns one output row (tx) of a 16x16 tile, for 4 batch rows.
// Wave = 4 m-tiles x 16 rows, walking the same k columns in lockstep so x
// addresses are wave-uniform (scalar loads). Decode: idx[s] = 9-bit window
// ending at chunk s of the kv=4 bitstream; thread's row tx needs trellis
// words 2tx-1, 2tx, 2tx+1. Word 2tx-1 comes from lane tx-1 via shfl_up.
//
// Round-4: occupancy push. The kernel is latency-bound on the per-kk
// {LDS gather batch -> FMA} chain; 5.4 waves/SIMD wasn't enough TLP.
//  - __launch_bounds__(256, 8): 8 blocks/CU (thread-limit max). Round-3's
//    register diet (~56 live VGPR) makes this feasible without spill.
//  - SEG 16->32: 2752 blocks fills the 2048 resident-block capacity and
//    halves the per-wave serial path (4 gather->FMA rounds). Atomic depth
//    64/addr (depth 16->32 was already shown free).
__global__ __launch_bounds__(256, 8) void tcq_kernel(
    const float* __restrict__ inp,       // [4][4096]
    const int* __restrict__ trellis1,    // [688*128][32]
    const int* __restrict__ trellis2,    // [688*128][32]
    const float* __restrict__ tlut,      // [512][2]
    float* __restrict__ out)             // [4][11008], pre-zeroed
{
    __shared__ float lut0[512];
    __shared__ float lut1[512];
    {
        const float2* src = reinterpret_cast<const float2*>(tlut);
        float2 a = src[threadIdx.x];
        float2 b = src[threadIdx.x + 256];
        lut0[threadIdx.x]       = a.x;
        lut1[threadIdx.x]       = a.y;
        lut0[threadIdx.x + 256] = b.x;
        lut1[threadIdx.x + 256] = b.y;
    }
    __syncthreads();

    const int tid  = threadIdx.x;
    const int lane = tid & 63;
    const int wid  = tid >> 6;
    const int tx   = lane & 15;          // row within tile
    const int mt   = lane >> 4;          // m-tile within wave (0..3)
    const int mo   = blockIdx.x * 16 + wid * 4 + mt;   // global m-tile (0..687)
    const int m    = mo * 16 + tx;       // output row
    const int ko0  = blockIdx.y * KO_PER_SEG;
    const int part = blockIdx.z;

    const int* __restrict__ tre =
        (part ? trellis2 : trellis1) + (mo * KO + ko0) * NW + 2 * tx;
    const float* __restrict__ xbase = inp + part * 2048 + ko0 * 16;

    // ---- all trellis words for this segment: one HBM latency window
    int2 w[KO_PER_SEG];
    #pragma unroll
    for (int kk = 0; kk < KO_PER_SEG; ++kk)
        w[kk] = *reinterpret_cast<const int2*>(tre + kk * NW);

    // ---- neighbor word (2tx-1) = lane tx-1's w.y; 0 for tx==0
    int wm1[KO_PER_SEG];
    #pragma unroll
    for (int kk = 0; kk < KO_PER_SEG; ++kk) {
        int t = __shfl_up(w[kk].y, 1, 16);
        wm1[kk] = (tx == 0) ? 0 : t;
    }

    // even-k and odd-k partial sums per batch (8 independent FMA chains)
    float accE[4] = {0.f, 0.f, 0.f, 0.f};
    float accO[4] = {0.f, 0.f, 0.f, 0.f};

    #pragma unroll
    for (int kk = 0; kk < KO_PER_SEG; ++kk) {
        unsigned comb0 = (unsigned(wm1[kk])  << 16) | (unsigned(w[kk].x) & 0xFFFFu);
        unsigned comb1 = (unsigned(w[kk].x) << 16) | (unsigned(w[kk].y) & 0xFFFFu);

        // batch the 16 b32 LUT gathers so lgkmcnt waits stage
        float wv0[8], wv1[8];
        #pragma unroll
        for (int j = 0; j < 8; ++j) {
            unsigned comb = (j < 4) ? comb0 : comb1;
            const int shift = 12 - 4 * (j & 3);
            unsigned idx = (comb >> shift) & 0x1FFu;
            wv0[j] = lut0[idx];
            wv1[j] = lut1[idx];
        }

        // x per j: 4 batch rows x float2 (wave-uniform -> scalar loads)
        const float* xt = xbase + kk * 16;
        #pragma unroll
        for (int j = 0; j < 8; ++j) {
            #pragma unroll
            for (int b = 0; b < 4; ++b) {
                float2 xv = *reinterpret_cast<const float2*>(
                    xt + b * IN_FEATURES + 2 * j);
                accE[b] = fmaf(wv0[j], xv.x, accE[b]);
                accO[b] = fmaf(wv1[j], xv.y, accO[b]);
            }
        }
    }

    #pragma unroll
    for (int b = 0; b < 4; ++b) {
        atomicAdd(&out[b * OUT_FEATURES + m], accE[b] + accO[b]);
    }
}

extern "C" void kernel_launch(void* const* d_in, const int* in_sizes, int n_in,
                              void* d_out, int out_size, void* d_ws, size_t ws_size,
                              hipStream_t stream) {
    const float* inp  = (const float*)d_in[0];
    const int*   t1   = (const int*)d_in[1];
    const int*   t2   = (const int*)d_in[2];
    const float* tlut = (const float*)d_in[3];
    float* out = (float*)d_out;

    hipMemsetAsync(out, 0, (size_t)out_size * sizeof(float), stream);

    dim3 grid(43, SEG, 2);   // 43 groups of 16 m-tiles, 32 k-segments, 2 partitions
    dim3 block(256);
    hipLaunchKernelGGL(tcq_kernel, grid, block, 0, stream,
                       inp, t1, t2, tlut, out);
}